// Round 4
// baseline (167.478 us; speedup 1.0000x reference)
//
#include <hip/hip_runtime.h>
#include <cstddef>

#define T_STEPS 1024
#define BATCH   32768
#define G1      50
#define H1      32
#define G2      20

__device__ __forceinline__ float softplus_f(float x) {
    // jax.nn.softplus = max(x,0) + log1p(exp(-|x|))
    float e = __expf(-fabsf(x));
    return fmaxf(x, 0.0f) + __logf(1.0f + e);
}

// One BLOCK (1 wave, 64 lanes) per time step t. Writes a[t] = dt * beta(t).
__global__ __launch_bounds__(64) void beta_kernel(
    const float* __restrict__ t_steps,
    const float* __restrict__ grid1,      // [50]
    const float* __restrict__ spline_w1,  // [50, 32] (g, j)
    const float* __restrict__ base_w1,    // [32]
    const float* __restrict__ grid2,      // [20]
    const float* __restrict__ spline_w2,  // [640]  index j*20+g
    const float* __restrict__ base_w2,    // [32]
    float* __restrict__ a_out)            // [1024] out: dt*beta
{
    __shared__ float se[G1];
    __shared__ float sh[H1];

    const int t    = blockIdx.x;
    const int lane = threadIdx.x;
    const float x  = t_steps[t];

    if (lane < G1) {
        float d = x - grid1[lane];
        se[lane] = __expf(-10.0f * d * d);
    }
    __syncthreads();

    if (lane < H1) {
        float acc = x * base_w1[lane];
        #pragma unroll
        for (int g = 0; g < G1; ++g)
            acc = fmaf(se[g], spline_w1[g * H1 + lane], acc);  // LDS broadcast
        sh[lane] = acc;
    }
    __syncthreads();

    // layer 2: 640 spline terms, 10 per lane; plus base term for lanes < 32
    float acc = 0.0f;
    #pragma unroll
    for (int k = 0; k < 10; ++k) {
        int p = lane + 64 * k;        // 0..639
        int j = p / G2;
        int g = p - j * G2;
        float d = sh[j] - grid2[g];
        acc = fmaf(__expf(-10.0f * d * d), spline_w2[p], acc);
    }
    if (lane < H1) acc = fmaf(sh[lane], base_w2[lane], acc);

    // 64-lane butterfly reduce
    #pragma unroll
    for (int ofs = 32; ofs >= 1; ofs >>= 1)
        acc += __shfl_xor(acc, ofs, 64);

    if (lane == 0) {
        float dt = t_steps[1] - t_steps[0];
        a_out[t] = dt * softplus_f(acc);
    }
}

// ILP-2 scan: each thread owns TWO adjacent batch elements and stores a
// float2 (dwordx2) per step. vs the previous 1-elem/thread version:
//  - store instruction count halves (each vmcnt slot covers 2x the bytes
//    -> deeper write pipeline per wave, attacking the suspected
//    outstanding-store throttle),
//  - the two independent recurrence chains interleave, hiding dependent
//    VALU latency at 1 wave/SIMD.
// Issue cost: ~17 wave-insts/step * 2cy * 1024 steps = 14.5 us << 21.3 us
// write floor, so this config stays write-BW bound by construction.
// 256 blocks x 64 threads = 1 wave per CU on all 256 CUs.
__global__ __launch_bounds__(64) void scan_kernel(
    const float* __restrict__ t_steps,
    const float* __restrict__ initial_I,
    const float* __restrict__ gamma_param,
    const float* __restrict__ a_in,   // [1024] dt*beta
    float* __restrict__ out)          // [T, B]
{
    __shared__ float4 sa4[T_STEPS / 4];
    const int lane = threadIdx.x;
    {
        const float4* g4 = (const float4*)a_in;
        #pragma unroll
        for (int i = 0; i < T_STEPS / 4 / 64; ++i)   // 4 iters
            sa4[lane + i * 64] = g4[lane + i * 64];
    }
    __syncthreads();

    const int b0 = blockIdx.x * 128 + lane * 2;      // two adjacent b per thread
    const float2 iv = *(const float2*)(initial_I + b0);
    float I0 = iv.x, I1 = iv.y;
    float S0 = 1.0f - I0, S1 = 1.0f - I1;
    const float gamma = softplus_f(gamma_param[0]);
    const float dt = t_steps[1] - t_steps[0];
    const float c = fmaf(-dt, gamma, 1.0f);          // 1 - dt*gamma
    float2* __restrict__ outp = (float2*)(out + b0);

    // 16 steps per body: 4x ds_read_b128 hoisted, then 16 ILP-2 chains + stores
    #pragma unroll 1
    for (int tb = 0; tb < T_STEPS; tb += 16) {
        float4 q[4];
        #pragma unroll
        for (int k = 0; k < 4; ++k) q[k] = sa4[tb / 4 + k];
        const float* av = (const float*)q;
        #pragma unroll
        for (int k = 0; k < 16; ++k) {
            float a  = av[k];
            float f0 = fmaf(a, S0, c);       // c + a*S   (old S)
            float f1 = fmaf(a, S1, c);
            float u0 = fmaf(-a, I0, 1.0f);   // 1 - a*I   (old I)
            float u1 = fmaf(-a, I1, 1.0f);
            float In0 = I0 * f0;
            float In1 = I1 * f1;
            float Sn0 = S0 * u0;
            float Sn1 = S1 * u1;
            I0 = fminf(fmaxf(In0, 0.0f), 5.0f);
            I1 = fminf(fmaxf(In1, 0.0f), 5.0f);
            S0 = fminf(fmaxf(Sn0, 0.0f), 5.0f);
            S1 = fminf(fmaxf(Sn1, 0.0f), 5.0f);
            float2 v; v.x = I0; v.y = I1;
            outp[(size_t)(tb + k) * (BATCH / 2)] = v;
        }
    }
}

extern "C" void kernel_launch(void* const* d_in, const int* in_sizes, int n_in,
                              void* d_out, int out_size, void* d_ws, size_t ws_size,
                              hipStream_t stream) {
    const float* t_steps     = (const float*)d_in[0];
    const float* initial_I   = (const float*)d_in[1];
    const float* grid1       = (const float*)d_in[2];
    const float* spline_w1   = (const float*)d_in[3];
    const float* base_w1     = (const float*)d_in[4];
    const float* grid2       = (const float*)d_in[5];
    const float* spline_w2   = (const float*)d_in[6];
    const float* base_w2     = (const float*)d_in[7];
    const float* gamma_param = (const float*)d_in[8];
    float* out = (float*)d_out;
    float* a_t = (float*)d_ws;   // 1024 floats: dt*beta(t)

    beta_kernel<<<T_STEPS, 64, 0, stream>>>(
        t_steps, grid1, spline_w1, base_w1, grid2, spline_w2, base_w2, a_t);
    scan_kernel<<<BATCH / 128, 64, 0, stream>>>(
        t_steps, initial_I, gamma_param, a_t, out);
}

// Round 5
// 157.593 us; speedup vs baseline: 1.0627x; 1.0627x over previous
//
#include <hip/hip_runtime.h>
#include <cstddef>

#define T_STEPS 1024
#define BATCH   32768
#define G1      50
#define H1      32
#define G2      20

__device__ __forceinline__ float softplus_f(float x) {
    // jax.nn.softplus = max(x,0) + log1p(exp(-|x|))
    float e = __expf(-fabsf(x));
    return fmaxf(x, 0.0f) + __logf(1.0f + e);
}

// One BLOCK (1 wave, 64 lanes) per time step t. Writes a[t] = dt * beta(t).
__global__ __launch_bounds__(64) void beta_kernel(
    const float* __restrict__ t_steps,
    const float* __restrict__ grid1,      // [50]
    const float* __restrict__ spline_w1,  // [50, 32] (g, j)
    const float* __restrict__ base_w1,    // [32]
    const float* __restrict__ grid2,      // [20]
    const float* __restrict__ spline_w2,  // [640]  index j*20+g
    const float* __restrict__ base_w2,    // [32]
    float* __restrict__ a_out)            // [1024] out: dt*beta
{
    __shared__ float se[G1];
    __shared__ float sh[H1];

    const int t    = blockIdx.x;
    const int lane = threadIdx.x;
    const float x  = t_steps[t];

    if (lane < G1) {
        float d = x - grid1[lane];
        se[lane] = __expf(-10.0f * d * d);
    }
    __syncthreads();

    if (lane < H1) {
        float acc = x * base_w1[lane];
        #pragma unroll
        for (int g = 0; g < G1; ++g)
            acc = fmaf(se[g], spline_w1[g * H1 + lane], acc);  // LDS broadcast
        sh[lane] = acc;
    }
    __syncthreads();

    // layer 2: 640 spline terms, 10 per lane; plus base term for lanes < 32
    float acc = 0.0f;
    #pragma unroll
    for (int k = 0; k < 10; ++k) {
        int p = lane + 64 * k;        // 0..639
        int j = p / G2;
        int g = p - j * G2;
        float d = sh[j] - grid2[g];
        acc = fmaf(__expf(-10.0f * d * d), spline_w2[p], acc);
    }
    if (lane < H1) acc = fmaf(sh[lane], base_w2[lane], acc);

    // 64-lane butterfly reduce
    #pragma unroll
    for (int ofs = 32; ofs >= 1; ofs >>= 1)
        acc += __shfl_xor(acc, ofs, 64);

    if (lane == 0) {
        float dt = t_steps[1] - t_steps[0];
        a_out[t] = dt * softplus_f(acc);
    }
}

// Burst-store scan. R0 baseline (interleaved stores, depth<=16) gave scan
// ~55-75us (~2 TB/s effective); R4's ILP-2 @ 1 wave/CU regressed (-10us)
// because halving waves halved store-latency hiding. This version:
//  - 512 waves (256 blocks x 128 thr, 1 elem/thread) = max TLP for B=32768
//  - per outer iter: compute 64 steps into 64 statically-indexed staging
//    regs r[64] (stays in VGPRs, ~140 total, no occupancy cost at 2 wv/CU),
//    then burst 64 dword stores from distinct regs.
//  - worst-case compiler schedule (vmcnt(0) drain + compute + issue) =
//    ~2440 cy / 64 steps = 38 cy/step < 48 cy/step HBM drain floor
//    -> write-BW bound by construction; best case 8 MB stores in flight
//    (64 x 256B x 512 waves) >> 2.3 MB needed to saturate 6.5 TB/s.
__global__ __launch_bounds__(128) void scan_kernel(
    const float* __restrict__ t_steps,
    const float* __restrict__ initial_I,
    const float* __restrict__ gamma_param,
    const float* __restrict__ a_in,   // [1024] dt*beta
    float* __restrict__ out)          // [T, B]
{
    __shared__ float4 sa4[T_STEPS / 4];
    {
        const float4* g4 = (const float4*)a_in;
        #pragma unroll
        for (int i = 0; i < T_STEPS / 4 / 128; ++i)   // 2 iters
            sa4[threadIdx.x + i * 128] = g4[threadIdx.x + i * 128];
    }
    __syncthreads();

    const int b = blockIdx.x * 128 + threadIdx.x;
    float I = initial_I[b];
    float S = 1.0f - I;
    const float gamma = softplus_f(gamma_param[0]);
    const float dt = t_steps[1] - t_steps[0];
    const float c = fmaf(-dt, gamma, 1.0f);   // 1 - dt*gamma
    float* outp = out + b;

    #pragma unroll 1
    for (int tb = 0; tb < T_STEPS; tb += 64) {
        float4 q[16];
        #pragma unroll
        for (int k = 0; k < 16; ++k) q[k] = sa4[tb / 4 + k];
        const float* av = (const float*)q;

        float r[64];                          // staging regs (static idx only)
        #pragma unroll
        for (int k = 0; k < 64; ++k) {
            float a  = av[k];
            float f  = fmaf(a, S, c);        // c + a*S        (uses old S)
            float u  = fmaf(-a, I, 1.0f);    // 1 - a*I        (uses old I)
            float In = I * f;                // I + dt*(b*S*I - g*I)
            float Sn = S * u;                // S - dt*b*S*I
            I = fminf(fmaxf(In, 0.0f), 5.0f);
            S = fminf(fmaxf(Sn, 0.0f), 5.0f);
            r[k] = I;
        }

        #pragma unroll
        for (int k = 0; k < 64; ++k)
            outp[(size_t)(tb + k) * BATCH] = r[k];
    }
}

extern "C" void kernel_launch(void* const* d_in, const int* in_sizes, int n_in,
                              void* d_out, int out_size, void* d_ws, size_t ws_size,
                              hipStream_t stream) {
    const float* t_steps     = (const float*)d_in[0];
    const float* initial_I   = (const float*)d_in[1];
    const float* grid1       = (const float*)d_in[2];
    const float* spline_w1   = (const float*)d_in[3];
    const float* base_w1     = (const float*)d_in[4];
    const float* grid2       = (const float*)d_in[5];
    const float* spline_w2   = (const float*)d_in[6];
    const float* base_w2     = (const float*)d_in[7];
    const float* gamma_param = (const float*)d_in[8];
    float* out = (float*)d_out;
    float* a_t = (float*)d_ws;   // 1024 floats: dt*beta(t)

    beta_kernel<<<T_STEPS, 64, 0, stream>>>(
        t_steps, grid1, spline_w1, base_w1, grid2, spline_w2, base_w2, a_t);
    scan_kernel<<<BATCH / 128, 128, 0, stream>>>(
        t_steps, initial_I, gamma_param, a_t, out);
}